// Round 8
// baseline (380.663 us; speedup 1.0000x reference)
//
#include <hip/hip_runtime.h>
#include <math.h>

#define NCLS 10
#define NB   16
#define NG   60
#define NA   33600          // 160*160 + 80*80 + 40*40
#define BA   (NB*NA)        // 537600
#define NBLK_X 132          // ceil(NA/256)
#define NBLK_LOSS (NBLK_X*NB)

// ---- static device scratch (load-time zero; self-restoring across calls) ----
__device__ double g_part[NBLK_LOSS][4];     // per-loss-block partials (nfg, iou, obj, cls)
__device__ int    g_fcount[NB];             // fg count per image (reset by final_kernel)
__device__ int    g_nmatch[BA];             // all-zero between calls (self-cleaned by loss)
__device__ int    g_gsum[BA];               // all-zero between calls (self-cleaned by loss)
__device__ int    g_slot[BA];               // compact slot (valid for fg anchors only)
// compacted per-image fg-anchor data
__device__ float4 g_cbox [BA];              // [b][j] bx,by,bw,bh
__device__ float4 g_cmeta[BA];              // [b][j] xc, yc, S, anchor_id_bits
__device__ float  g_cD   [(size_t)NB*NCLS*NA];  // [b][c][j] class-major

__device__ __forceinline__ void anchor_geom(int a, int& H, int& W, float& s, int& h, int& w, int& lvl) {
  if (a < 25600)      { lvl = 0; H = 160; W = 160; s = 8.f;  h = a / 160;            w = a - h*160; }
  else if (a < 32000) { lvl = 1; H = 80;  W = 80;  s = 16.f; int r = a - 25600; h = r / 80;  w = r - h*80; }
  else                { lvl = 2; H = 40;  W = 40;  s = 32.f; int r = a - 32000; h = r / 40;  w = r - h*40; }
}

// monotone float->uint key (order-preserving for all finite floats)
__device__ __forceinline__ unsigned int fkey(float f) {
  unsigned int b = __float_as_uint(f);
  return (b & 0x80000000u) ? ~b : (b | 0x80000000u);
}

// ---- Kernel A: y-band GT filter -> fg test -> compact -> decode planes (fg only) ----
__global__ __launch_bounds__(256) void decode_kernel(const float* __restrict__ p0,
                                                     const float* __restrict__ p1,
                                                     const float* __restrict__ p2,
                                                     const float* __restrict__ lb) {
  __shared__ float lab[NG*5];
  __shared__ int   glist[NG];
  __shared__ int   gln;
  __shared__ int   wbase[4];
  __shared__ int   bbase_s;
  int b = blockIdx.y, tid = threadIdx.x;
  for (int i = tid; i < NG*5; i += 256) lab[i] = lb[(size_t)b*NG*5 + i];
  if (tid == 0) gln = 0;
  __syncthreads();

  // block anchor-band geometry (level boundaries 25600, 32000 are 256-aligned)
  int a0 = blockIdx.x * 256;
  int H, W, h0, w0, lvl; float st;
  anchor_geom(a0, H, W, st, h0, w0, lvl);
  int aL = a0 + 255; if (aL >= NA) aL = NA - 1;
  int Hx, Wx, h1, w1, l1; float st1;
  anchor_geom(aL, Hx, Wx, st1, h1, w1, l1);
  float ylo = ((float)h0 + 0.5f) * st;
  float yhi = ((float)h1 + 0.5f) * st;
  float rad = 2.5f * st;

  // per-GT y-band relevance filter (conservative)
  if (tid < NG) {
    float s0 = lab[tid*5] + lab[tid*5+1] + lab[tid*5+2] + lab[tid*5+3] + lab[tid*5+4];
    if (s0 > 0.f) {
      float gy = lab[tid*5+2], gh = lab[tid*5+4];
      float m = fmaxf(gh * 0.5f, rad);
      if ((gy - m < yhi) && (gy + m > ylo)) {
        int p = atomicAdd(&gln, 1);
        glist[p] = tid;
      }
    }
  }
  __syncthreads();

  int n = gln;
  if (n == 0) return;   // no GT can touch this band -> no fg anchors here

  int a = a0 + tid;
  bool valid = a < NA;
  int H2, W2, ht, wt, l2; float st2;
  anchor_geom(valid ? a : a0, H2, W2, st2, ht, wt, l2);
  float xc = ((float)wt + 0.5f) * st;
  float yc = ((float)ht + 0.5f) * st;

  int fg = 0;
  if (valid) {
    for (int q = 0; q < n; q++) {
      int g = glist[q];
      float gx = lab[g*5+1], gy = lab[g*5+2], gw = lab[g*5+3], gh = lab[g*5+4];
      float l  = xc - (gx - gw*0.5f);
      float r  = (gx + gw*0.5f) - xc;
      float t  = yc - (gy - gh*0.5f);
      float bo = (gy + gh*0.5f) - yc;
      float m1 = fminf(fminf(l, r), fminf(t, bo));
      float cl = xc - gx + rad, cr = gx + rad - xc, ct = yc - gy + rad, cb = gy + rad - yc;
      float m2 = fminf(fminf(cl, cr), fminf(ct, cb));
      if (m1 > 0.f || m2 > 0.f) { fg = 1; break; }
    }
  }

  // block-aggregated compaction: one atomic per block
  unsigned long long m = __ballot(fg != 0);
  int lane = tid & 63, wv = tid >> 6;
  if (lane == 0) wbase[wv] = __popcll(m);
  __syncthreads();
  if (tid == 0) {
    int t = 0;
    #pragma unroll
    for (int k = 0; k < 4; k++) { int c = wbase[k]; wbase[k] = t; t += c; }
    bbase_s = t ? atomicAdd(&g_fcount[b], t) : 0;
  }
  __syncthreads();

  if (fg) {
    // plane loads + transcendentals only for fg anchors
    const float* pp = (lvl == 0) ? p0 : ((lvl == 1) ? p1 : p2);
    size_t cs = (size_t)H * W;
    size_t base = (size_t)b * 15 * cs + (size_t)ht * W + wt;

    float tx = pp[base], ty = pp[base+cs], tw = pp[base+2*cs], th = pp[base+3*cs], to = pp[base+4*cs];
    float4 boxv = make_float4((tx + (float)wt) * st, (ty + (float)ht) * st,
                              __expf(tw) * st, __expf(th) * st);

    float so = 1.f / (1.f + __expf(-to));
    float S = 0.f;
    float Dl[NCLS];
    #pragma unroll
    for (int c = 0; c < NCLS; c++) {
      float xl = pp[base + (size_t)(5 + c) * cs];
      float sc = 1.f / (1.f + __expf(-xl));
      float p  = sqrtf(sc * so);
      float L  = __logf(p + 1e-12f);
      float M  = __logf(1.f - p + 1e-12f);
      S += M;
      Dl[c] = L - M;
    }

    int j = bbase_s + wbase[wv] + (int)__popcll(m & ((1ULL << lane) - 1ULL));
    size_t cb = (size_t)b * NA + j;
    g_cbox[cb]  = boxv;
    g_cmeta[cb] = make_float4(xc, yc, S, __int_as_float(a));
    #pragma unroll
    for (int c = 0; c < NCLS; c++) g_cD[((size_t)b*NCLS + c)*NA + j] = Dl[c];
    g_slot[b * NA + a] = j;
  }
}

// ---- Kernel B: one wave per (b,g): scan compact fg anchors, extract, dyn_k, scatter ----
__global__ __launch_bounds__(64) void topk_kernel(const float* __restrict__ lb) {
  int p = blockIdx.x;                  // pair id: b = p/NG, g = p%NG
  int lane = threadIdx.x;
  int b = p / NG, g = p - b * NG;

  const float* L = &lb[(size_t)p * 5];
  float l0 = L[0], l1 = L[1], l2 = L[2], l3 = L[3], l4 = L[4];
  if (!(l0 + l1 + l2 + l3 + l4 > 0.f)) return;

  int   gc = (int)l0;
  float gx = l1, gy = l2, gw = l3, gh = l4;
  float a1x = gx - gw*0.5f, a1y = gy - gh*0.5f, a2x = gx + gw*0.5f, a2y = gy + gh*0.5f;
  float garea = gw * gh;
  int F = g_fcount[b];
  const float4* CB = &g_cbox [(size_t)b*NA];
  const float4* CM = &g_cmeta[(size_t)b*NA];
  const float*  CD = &g_cD[((size_t)b*NCLS + gc)*NA];

  unsigned long long kv[10]; float iv[10];
  #pragma unroll
  for (int k = 0; k < 10; k++) { kv[k] = ~0ULL; iv[k] = 0.f; }

  #pragma unroll 2
  for (int j = lane; j < F; j += 64) {
    float4 B = CB[j];
    float4 M = CM[j];
    float Dv = CD[j];
    int a = __float_as_int(M.w);
    float b1x = B.x - B.z*0.5f, b1y = B.y - B.w*0.5f;
    float b2x = B.x + B.z*0.5f, b2y = B.y + B.w*0.5f;
    float wx = fminf(a2x, b2x) - fmaxf(a1x, b1x); wx = wx > 0.f ? wx : 0.f;
    float wy = fminf(a2y, b2y) - fmaxf(a1y, b1y); wy = wy > 0.f ? wy : 0.f;
    float inter = wx * wy;
    float iou = inter / (garea + B.z*B.w - inter + 1e-8f);
    float xc = M.x, yc = M.y;
    float rad = (a < 25600) ? 20.f : ((a < 32000) ? 40.f : 80.f);
    bool inb = fminf(fminf(xc - a1x, a2x - xc), fminf(yc - a1y, a2y - yc)) > 0.f;
    bool inc = fminf(fminf(xc - gx + rad, gx + rad - xc), fminf(yc - gy + rad, gy + rad - yc)) > 0.f;
    float cost = -(Dv + M.z) + 3.0f * (-__logf(iou + 1e-8f));
    if (!(inb && inc)) cost += 100000.0f;

    unsigned long long key = ((unsigned long long)fkey(cost) << 32) | (unsigned int)a;
    if (key < kv[9]) {
      kv[9] = key;
      #pragma unroll
      for (int k = 9; k > 0; k--) {
        if (kv[k] < kv[k-1]) { unsigned long long t = kv[k]; kv[k] = kv[k-1]; kv[k-1] = t; }
      }
    }
    if (iou > iv[9]) {
      iv[9] = iou;
      #pragma unroll
      for (int k = 9; k > 0; k--) {
        if (iv[k] > iv[k-1]) { float t = iv[k]; iv[k] = iv[k-1]; iv[k-1] = t; }
      }
    }
  }

  // phase 1: iou extraction (descending) -> ss -> dynk
  float ss = 0.f;
  for (int k = 0; k < 10; k++) {
    float m = iv[0];
    #pragma unroll
    for (int d = 1; d < 64; d <<= 1) m = fmaxf(m, __shfl_xor(m, d));
    if (m <= 0.f) break;                 // rest are zeros (uniform)
    ss += m;                             // descending order, same sum order as ref
    unsigned long long pm = __ballot(iv[0] == m);
    if (lane == __ffsll((unsigned long long)pm) - 1) {
      #pragma unroll
      for (int j2 = 0; j2 < 9; j2++) iv[j2] = iv[j2+1];
      iv[9] = 0.f;
    }
  }
  int dynk = (int)ss;
  if (dynk < 1)  dynk = 1;
  if (dynk > 10) dynk = 10;

  // phase 2: cost extraction (ascending), only dynk rounds, scatter inline
  for (int k = 0; k < dynk; k++) {
    unsigned long long m = kv[0];
    #pragma unroll
    for (int d = 1; d < 64; d <<= 1) {
      unsigned long long o = __shfl_xor(m, d);
      if (o < m) m = o;
    }
    if (m == ~0ULL) break;               // exhausted (uniform)
    if (lane == 0) {
      int a = (int)(unsigned int)(m & 0xFFFFFFFFu);
      atomicAdd(&g_nmatch[b*NA + a], 1);
      atomicAdd(&g_gsum[b*NA + a], g);
    }
    if (kv[0] == m) {                    // unique key -> exactly one lane pops
      #pragma unroll
      for (int j2 = 0; j2 < 9; j2++) kv[j2] = kv[j2+1];
      kv[9] = ~0ULL;
    }
  }
}

// ---- Kernel C: dedup (argmin over g), per-anchor losses, per-block partial store ----
__global__ __launch_bounds__(256) void loss_kernel(const float* __restrict__ p0,
                                                   const float* __restrict__ p1,
                                                   const float* __restrict__ p2,
                                                   const float* __restrict__ lb) {
  __shared__ float  lab[NG*5];
  __shared__ int    lval[NG];
  __shared__ double red[256*4];
  int b = blockIdx.y, tid = threadIdx.x;
  for (int i = tid; i < NG*5; i += 256) lab[i] = lb[(size_t)b*NG*5 + i];
  __syncthreads();
  if (tid < NG) {
    float s = lab[tid*5] + lab[tid*5+1] + lab[tid*5+2] + lab[tid*5+3] + lab[tid*5+4];
    lval[tid] = (s > 0.f) ? 1 : 0;
  }
  __syncthreads();

  int a = blockIdx.x * 256 + tid;
  double t_nfg = 0.0, t_iou = 0.0, t_obj = 0.0, t_cls = 0.0;

  if (a < NA) {
    int idx = b * NA + a;
    int H, W, h, w, lvl; float st;
    anchor_geom(a, H, W, st, h, w, lvl);
    const float* pp = (lvl == 0) ? p0 : ((lvl == 1) ? p1 : p2);
    size_t cs = (size_t)H * W;
    size_t base = (size_t)b * 15 * cs + (size_t)h * W + w;

    float x  = pp[base + 4*cs];
    int   nm = g_nmatch[idx];
    float t  = (nm > 0) ? 1.f : 0.f;
    float bce = fmaxf(x, 0.f) - x * t + log1pf(expf(-fabsf(x)));
    float pr  = 1.f / (1.f + expf(-x));
    float pt  = (nm > 0) ? pr : (1.f - pr);
    float wf  = (nm > 0) ? 0.25f : 0.75f;
    float om  = 1.f - pt;
    t_obj = (double)(bce * wf * om * om);

    if (nm > 0) {
      t_nfg = 1.0;
      int mgsum = g_gsum[idx];
      g_nmatch[idx] = 0;           // self-clean for next call
      g_gsum[idx]   = 0;
      int j = g_slot[idx];
      float4 B  = g_cbox [(size_t)b*NA + j];
      float4 Mt = g_cmeta[(size_t)b*NA + j];
      float pw = B.z, ph = B.w;
      float b1x = B.x - pw*0.5f, b1y = B.y - ph*0.5f, b2x = B.x + pw*0.5f, b2y = B.y + ph*0.5f;
      int mg;
      if (nm == 1) {
        mg = mgsum;
      } else {
        // matched => fg, so the 1e6 term reduces to validity only
        float xc = Mt.x, yc = Mt.y, S = Mt.z;
        float rad = 2.5f * st;
        const float* CDb = &g_cD[(size_t)b*NCLS*NA];
        float best = INFINITY; int bg = 0;
        for (int g = 0; g < NG; g++) {
          float gx = lab[g*5+1], gy = lab[g*5+2], gw = lab[g*5+3], gh = lab[g*5+4];
          int gcl = (int)lab[g*5];
          int v = lval[g];
          float a1x = gx - gw*0.5f, a1y = gy - gh*0.5f, a2x = gx + gw*0.5f, a2y = gy + gh*0.5f;
          float wx = fminf(a2x, b2x) - fmaxf(a1x, b1x); wx = wx > 0.f ? wx : 0.f;
          float wy = fminf(a2y, b2y) - fmaxf(a1y, b1y); wy = wy > 0.f ? wy : 0.f;
          float inter = wx * wy;
          float iou = inter / (gw*gh + pw*ph - inter + 1e-8f);
          float l = xc - a1x, r = a2x - xc, tt = yc - a1y, bo = a2y - yc;
          bool inb = (fminf(fminf(l, r), fminf(tt, bo)) > 0.f) && v;
          float cl = xc - gx + rad, cr = gx + rad - xc, ct = yc - gy + rad, cb = gy + rad - yc;
          bool inc = (fminf(fminf(cl, cr), fminf(ct, cb)) > 0.f) && v;
          float clsc = -(CDb[(size_t)gcl*NA + j] + S);
          float cost = clsc + 3.0f * (-__logf(iou + 1e-8f));
          if (!(inb && inc)) cost += 100000.0f;
          if (!v)            cost += 1000000.0f;
          if (cost < best) { best = cost; bg = g; }   // strict < : first-index tie-break
        }
        mg = bg;
      }

      float gx = lab[mg*5+1], gy = lab[mg*5+2], gw = lab[mg*5+3], gh = lab[mg*5+4];
      int mcls = (int)lab[mg*5];
      float a1x = gx - gw*0.5f, a1y = gy - gh*0.5f, a2x = gx + gw*0.5f, a2y = gy + gh*0.5f;
      float wx = fminf(a2x, b2x) - fmaxf(a1x, b1x); wx = wx > 0.f ? wx : 0.f;
      float wy = fminf(a2y, b2y) - fmaxf(a1y, b1y); wy = wy > 0.f ? wy : 0.f;
      float inter = wx * wy;
      float miou = inter / (gw*gh + pw*ph - inter + 1e-8f);  // == forward-loss IoU bit-exact

      t_iou = (double)(1.f - miou * miou);

      float sc = 0.f;
      #pragma unroll
      for (int c = 0; c < NCLS; c++) {
        float xl = pp[base + (size_t)(5 + c) * cs];
        float ctg = (c == mcls) ? miou : 0.f;
        sc += fmaxf(xl, 0.f) - xl * ctg + log1pf(expf(-fabsf(xl)));
      }
      t_cls = (double)sc;
    }
  }

  red[tid] = t_nfg; red[256+tid] = t_iou; red[512+tid] = t_obj; red[768+tid] = t_cls;
  __syncthreads();
  for (int s = 128; s > 0; s >>= 1) {
    if (tid < s) {
      red[tid]     += red[tid+s];
      red[256+tid] += red[256+tid+s];
      red[512+tid] += red[512+tid+s];
      red[768+tid] += red[768+tid+s];
    }
    __syncthreads();
  }
  if (tid == 0) {
    int blk = b * NBLK_X + blockIdx.x;
    g_part[blk][0] = red[0];
    g_part[blk][1] = red[256];
    g_part[blk][2] = red[512];
    g_part[blk][3] = red[768];
  }
}

// ---- Kernel D: reduce per-block partials, finalize, reset fcount ----
__global__ __launch_bounds__(256) void final_kernel(float* __restrict__ out) {
  __shared__ double red[256];
  int tid = threadIdx.x;
  int cat = tid & 3;
  double s = 0.0;
  for (int blk = tid >> 2; blk < NBLK_LOSS; blk += 64) s += g_part[blk][cat];
  red[tid] = s;
  __syncthreads();
  for (int st = 128; st >= 4; st >>= 1) {
    if (tid < st) red[tid] += red[tid + st];
    __syncthreads();
  }
  if (tid == 0) {
    double nfg = red[0];
    double num = (nfg < 1.0) ? 1.0 : nfg;
    float li = (float)(red[1] / num);
    float lo = (float)(red[2] / num);
    float lc = (float)(red[3] / num);
    out[0] = 5.0f * li + lo;   // REG_W * loss_iou + loss_obj
    out[1] = li;
    out[2] = lo;
    out[3] = lc;
  }
  if (tid < NB) g_fcount[tid] = 0;   // self-restore for next call
}

extern "C" void kernel_launch(void* const* d_in, const int* in_sizes, int n_in,
                              void* d_out, int out_size, void* d_ws, size_t ws_size,
                              hipStream_t stream) {
  const float* p0 = (const float*)d_in[0];
  const float* p1 = (const float*)d_in[1];
  const float* p2 = (const float*)d_in[2];
  const float* lb = (const float*)d_in[3];
  float* out = (float*)d_out;

  hipLaunchKernelGGL(decode_kernel, dim3(NBLK_X, NB), dim3(256), 0, stream, p0, p1, p2, lb);
  hipLaunchKernelGGL(topk_kernel,   dim3(NB*NG), dim3(64), 0, stream, lb);
  hipLaunchKernelGGL(loss_kernel,   dim3(NBLK_X, NB), dim3(256), 0, stream, p0, p1, p2, lb);
  hipLaunchKernelGGL(final_kernel,  dim3(1), dim3(256), 0, stream, out);
}

// Round 10
// 189.324 us; speedup vs baseline: 2.0106x; 2.0106x over previous
//
#include <hip/hip_runtime.h>
#include <math.h>

#define NCLS 10
#define NB   16
#define NG   60
#define NA   33600          // 160*160 + 80*80 + 40*40
#define BA   (NB*NA)        // 537600
#define NBLK_X 132          // ceil(NA/256)
#define NBLK_LOSS (NBLK_X*NB)

// ---- static device scratch (load-time zero; self-restoring across calls) ----
__device__ double g_part[NBLK_LOSS][4];     // per-loss-block partials (nfg, iou, obj, cls)
__device__ int    g_fcount[NB];             // fg count per image (reset by final_kernel)
__device__ int    g_nmatch[BA];             // all-zero between calls (self-cleaned by loss)
__device__ int    g_gsum[BA];               // all-zero between calls (self-cleaned by loss)
__device__ int    g_slot[BA];               // compact slot (valid for fg anchors only)
// compacted per-image fg-anchor data
__device__ float4 g_cbox [BA];              // [b][j] bx,by,bw,bh
__device__ float4 g_cmeta[BA];              // [b][j] xc, yc, S, anchor_id_bits
__device__ float  g_cD   [(size_t)NB*NCLS*NA];  // [b][c][j] class-major

__device__ __forceinline__ void anchor_geom(int a, int& H, int& W, float& s, int& h, int& w, int& lvl) {
  if (a < 25600)      { lvl = 0; H = 160; W = 160; s = 8.f;  h = a / 160;            w = a - h*160; }
  else if (a < 32000) { lvl = 1; H = 80;  W = 80;  s = 16.f; int r = a - 25600; h = r / 80;  w = r - h*80; }
  else                { lvl = 2; H = 40;  W = 40;  s = 32.f; int r = a - 32000; h = r / 40;  w = r - h*40; }
}

// monotone float->uint key (order-preserving for all finite floats)
__device__ __forceinline__ unsigned int fkey(float f) {
  unsigned int b = __float_as_uint(f);
  return (b & 0x80000000u) ? ~b : (b | 0x80000000u);
}

// ---- Kernel A: y-band GT filter -> fg test -> compact -> decode planes (fg only) ----
__global__ __launch_bounds__(256) void decode_kernel(const float* __restrict__ p0,
                                                     const float* __restrict__ p1,
                                                     const float* __restrict__ p2,
                                                     const float* __restrict__ lb) {
  __shared__ float lab[NG*5];
  __shared__ int   glist[NG];
  __shared__ int   gln;
  __shared__ int   wbase[4];
  __shared__ int   bbase_s;
  int b = blockIdx.y, tid = threadIdx.x;
  for (int i = tid; i < NG*5; i += 256) lab[i] = lb[(size_t)b*NG*5 + i];
  if (tid == 0) gln = 0;
  __syncthreads();

  // block anchor-band geometry (level boundaries 25600, 32000 are 256-aligned)
  int a0 = blockIdx.x * 256;
  int H, W, h0, w0, lvl; float st;
  anchor_geom(a0, H, W, st, h0, w0, lvl);
  int aL = a0 + 255; if (aL >= NA) aL = NA - 1;
  int Hx, Wx, h1, w1, l1; float st1;
  anchor_geom(aL, Hx, Wx, st1, h1, w1, l1);
  float ylo = ((float)h0 + 0.5f) * st;
  float yhi = ((float)h1 + 0.5f) * st;
  float rad = 2.5f * st;

  // per-GT y-band relevance filter (conservative)
  if (tid < NG) {
    float s0 = lab[tid*5] + lab[tid*5+1] + lab[tid*5+2] + lab[tid*5+3] + lab[tid*5+4];
    if (s0 > 0.f) {
      float gy = lab[tid*5+2], gh = lab[tid*5+4];
      float m = fmaxf(gh * 0.5f, rad);
      if ((gy - m < yhi) && (gy + m > ylo)) {
        int p = atomicAdd(&gln, 1);
        glist[p] = tid;
      }
    }
  }
  __syncthreads();

  int n = gln;
  if (n == 0) return;   // no GT can touch this band -> no fg anchors here

  int a = a0 + tid;
  bool valid = a < NA;
  int H2, W2, ht, wt, l2; float st2;
  anchor_geom(valid ? a : a0, H2, W2, st2, ht, wt, l2);
  float xc = ((float)wt + 0.5f) * st;
  float yc = ((float)ht + 0.5f) * st;

  int fg = 0;
  if (valid) {
    for (int q = 0; q < n; q++) {
      int g = glist[q];
      float gx = lab[g*5+1], gy = lab[g*5+2], gw = lab[g*5+3], gh = lab[g*5+4];
      float l  = xc - (gx - gw*0.5f);
      float r  = (gx + gw*0.5f) - xc;
      float t  = yc - (gy - gh*0.5f);
      float bo = (gy + gh*0.5f) - yc;
      float m1 = fminf(fminf(l, r), fminf(t, bo));
      float cl = xc - gx + rad, cr = gx + rad - xc, ct = yc - gy + rad, cb = gy + rad - yc;
      float m2 = fminf(fminf(cl, cr), fminf(ct, cb));
      if (m1 > 0.f || m2 > 0.f) { fg = 1; break; }
    }
  }

  // block-aggregated compaction: one atomic per block
  unsigned long long m = __ballot(fg != 0);
  int lane = tid & 63, wv = tid >> 6;
  if (lane == 0) wbase[wv] = __popcll(m);
  __syncthreads();
  if (tid == 0) {
    int t = 0;
    #pragma unroll
    for (int k = 0; k < 4; k++) { int c = wbase[k]; wbase[k] = t; t += c; }
    bbase_s = t ? atomicAdd(&g_fcount[b], t) : 0;
  }
  __syncthreads();

  if (fg) {
    // plane loads + transcendentals only for fg anchors
    const float* pp = (lvl == 0) ? p0 : ((lvl == 1) ? p1 : p2);
    size_t cs = (size_t)H * W;
    size_t base = (size_t)b * 15 * cs + (size_t)ht * W + wt;

    float tx = pp[base], ty = pp[base+cs], tw = pp[base+2*cs], th = pp[base+3*cs], to = pp[base+4*cs];
    float4 boxv = make_float4((tx + (float)wt) * st, (ty + (float)ht) * st,
                              __expf(tw) * st, __expf(th) * st);

    float so = 1.f / (1.f + __expf(-to));
    float S = 0.f;
    float Dl[NCLS];
    #pragma unroll
    for (int c = 0; c < NCLS; c++) {
      float xl = pp[base + (size_t)(5 + c) * cs];
      float sc = 1.f / (1.f + __expf(-xl));
      float p  = sqrtf(sc * so);
      float L  = __logf(p + 1e-12f);
      float M  = __logf(1.f - p + 1e-12f);
      S += M;
      Dl[c] = L - M;
    }

    int j = bbase_s + wbase[wv] + (int)__popcll(m & ((1ULL << lane) - 1ULL));
    size_t cb = (size_t)b * NA + j;
    g_cbox[cb]  = boxv;
    g_cmeta[cb] = make_float4(xc, yc, S, __int_as_float(a));
    #pragma unroll
    for (int c = 0; c < NCLS; c++) g_cD[((size_t)b*NCLS + c)*NA + j] = Dl[c];
    g_slot[b * NA + a] = j;
  }
}

// ---- Kernel B: per-(b,g) block: tier-1 enumeration + iou-only scan + dyn_k + scatter ----
__global__ __launch_bounds__(256) void topk_kernel(const float* __restrict__ lb) {
  __shared__ unsigned long long keyarr[256];
  __shared__ unsigned long long kvl[4][10];
  __shared__ float              ioul[4][10];
  __shared__ int                wcnt[4];
  __shared__ int                sdynk;
  __shared__ int                st1cnt;

  int fid = blockIdx.x;                 // XCD-clustering remap: images {2r,2r+1} -> XCD r
  int t8 = fid >> 3;
  int b  = ((fid & 7) << 1) + (t8 >= 60 ? 1 : 0);
  int g  = t8 - (t8 >= 60 ? 60 : 0);
  int tid = threadIdx.x, lane = tid & 63, wv = tid >> 6;

  const float* L = &lb[((size_t)b*NG + g)*5];
  float l0 = L[0], l1 = L[1], l2 = L[2], l3 = L[3], l4 = L[4];
  if (!(l0 + l1 + l2 + l3 + l4 > 0.f)) return;

  int   gc = (int)l0;
  float gx = l1, gy = l2, gw = l3, gh = l4;
  float a1x = gx - gw*0.5f, a1y = gy - gh*0.5f, a2x = gx + gw*0.5f, a2y = gy + gh*0.5f;
  float garea = gw * gh;
  int F = g_fcount[b];
  const float4* CB = &g_cbox [(size_t)b*NA];
  const float4* CM = &g_cmeta[(size_t)b*NA];
  const float*  CD = &g_cD[((size_t)b*NCLS + gc)*NA];

  // ---- Phase E: tier-1 (in_box && in_ctr) enumeration, one cell per thread ----
  // in_ctr => |xc-gx|<2.5*st && |yc-gy|<2.5*st => cell in 6x6 window per level.
  unsigned long long t1key = ~0ULL;
  if (tid < 108) {
    int lv   = tid / 36;                 // 0..2
    int cell = tid - lv*36;              // 0..35
    int dy   = cell / 6 - 2;             // -2..3
    int dx   = cell - (cell/6)*6 - 2;    // -2..3
    int   W  = (lv == 0) ? 160 : ((lv == 1) ? 80 : 40);
    float st = (lv == 0) ? 8.f : ((lv == 1) ? 16.f : 32.f);
    int   ab = (lv == 0) ? 0 : ((lv == 1) ? 25600 : 32000);
    int wc = (int)floorf(gx / st - 0.5f) + dx;
    int hc = (int)floorf(gy / st - 0.5f) + dy;
    if (wc >= 0 && wc < W && hc >= 0 && hc < W) {
      float xc = ((float)wc + 0.5f) * st;
      float yc = ((float)hc + 0.5f) * st;
      float rad = 2.5f * st;
      bool inb = fminf(fminf(xc - a1x, a2x - xc), fminf(yc - a1y, a2y - yc)) > 0.f;
      bool inc = fminf(fminf(xc - gx + rad, gx + rad - xc), fminf(yc - gy + rad, gy + rad - yc)) > 0.f;
      if (inb && inc) {
        int a = ab + hc * W + wc;        // in_ctr => fg => slot valid
        int j = g_slot[b*NA + a];
        float4 B = CB[j];
        float Dv = CD[j];
        float S  = CM[j].z;
        float b1x = B.x - B.z*0.5f, b1y = B.y - B.w*0.5f;
        float b2x = B.x + B.z*0.5f, b2y = B.y + B.w*0.5f;
        float wx = fminf(a2x, b2x) - fmaxf(a1x, b1x); wx = wx > 0.f ? wx : 0.f;
        float wy = fminf(a2y, b2y) - fmaxf(a1y, b1y); wy = wy > 0.f ? wy : 0.f;
        float inter = wx * wy;
        float iou = inter / (garea + B.z*B.w - inter + 1e-8f);
        float cost = -(Dv + S) + 3.0f * (-__logf(iou + 1e-8f));   // tier-1: no penalties
        t1key = ((unsigned long long)fkey(cost) << 32) | (unsigned int)a;
      }
    }
  }
  keyarr[tid] = t1key;
  {
    unsigned long long bal = __ballot(t1key != ~0ULL);
    if (lane == 0) wcnt[wv] = __popcll(bal);
  }

  // ---- Phase S: iou-only scan over all compacted fg anchors ----
  float iv[10];
  #pragma unroll
  for (int k = 0; k < 10; k++) iv[k] = 0.f;
  #pragma unroll 2
  for (int j = tid; j < F; j += 256) {
    float4 B = CB[j];
    float b1x = B.x - B.z*0.5f, b1y = B.y - B.w*0.5f;
    float b2x = B.x + B.z*0.5f, b2y = B.y + B.w*0.5f;
    float wx = fminf(a2x, b2x) - fmaxf(a1x, b1x); wx = wx > 0.f ? wx : 0.f;
    float wy = fminf(a2y, b2y) - fmaxf(a1y, b1y); wy = wy > 0.f ? wy : 0.f;
    float inter = wx * wy;
    float iou = inter / (garea + B.z*B.w - inter + 1e-8f);
    if (iou > iv[9]) {
      iv[9] = iou;
      #pragma unroll
      for (int k = 9; k > 0; k--) {
        if (iv[k] > iv[k-1]) { float t = iv[k]; iv[k] = iv[k-1]; iv[k-1] = t; }
      }
    }
  }
  // per-wave descending extraction -> sorted list in LDS
  for (int k = 0; k < 10; k++) {
    float m = iv[0];
    #pragma unroll
    for (int d = 1; d < 64; d <<= 1) m = fmaxf(m, __shfl_xor(m, d));
    if (lane == 0) ioul[wv][k] = m;
    unsigned long long pm = __ballot(iv[0] == m);
    if (lane == __ffsll((unsigned long long)pm) - 1) {
      #pragma unroll
      for (int j2 = 0; j2 < 9; j2++) iv[j2] = iv[j2+1];
      iv[9] = 0.f;
    }
  }
  __syncthreads();

  // tid 0: merge 4 sorted iou lists (descending) -> dyn_k
  if (tid == 0) {
    st1cnt = wcnt[0] + wcnt[1] + wcnt[2] + wcnt[3];
    int p_[4] = {0,0,0,0};
    float ss = 0.f;
    #pragma unroll 1
    for (int k = 0; k < 10; k++) {
      float best = ioul[0][p_[0]]; int bl = 0;
      #pragma unroll
      for (int l = 1; l < 4; l++) {
        float v = ioul[l][p_[l]];
        if (v > best) { best = v; bl = l; }
      }
      ss += best;                         // descending order, same sum order as ref
      if (p_[bl] < 9) p_[bl]++;
      else ioul[bl][9] = -INFINITY;       // list exhausted
    }
    int dynk = (int)ss;
    if (dynk < 1)  dynk = 1;
    if (dynk > 10) dynk = 10;
    sdynk = dynk;
  }
  __syncthreads();
  int dynk  = sdynk;
  int t1cnt = st1cnt;

  if (t1cnt >= 10) {
    // cost top-10 is entirely tier-1 (tier-2 >= 1e5 > any tier-1 cost <= ~332)
    if (wv == 0) {
      unsigned long long q0 = keyarr[lane], q1 = keyarr[lane+64],
                         q2 = keyarr[lane+128], q3 = keyarr[lane+192];
      // sort-4 network (ascending)
      { unsigned long long t;
        if (q1 < q0) { t=q0; q0=q1; q1=t; }
        if (q3 < q2) { t=q2; q2=q3; q3=t; }
        if (q2 < q0) { t=q0; q0=q2; q2=t; }
        if (q3 < q1) { t=q1; q1=q3; q3=t; }
        if (q2 < q1) { t=q1; q1=q2; q2=t; } }
      for (int k = 0; k < dynk; k++) {
        unsigned long long m = q0;
        #pragma unroll
        for (int d = 1; d < 64; d <<= 1) {
          unsigned long long o = __shfl_xor(m, d);
          if (o < m) m = o;
        }
        if (m == ~0ULL) break;            // defensive
        if (lane == 0) {
          int a = (int)(unsigned int)(m & 0xFFFFFFFFu);
          atomicAdd(&g_nmatch[b*NA + a], 1);
          atomicAdd(&g_gsum[b*NA + a], g);
        }
        if (q0 == m) { q0 = q1; q1 = q2; q2 = q3; q3 = ~0ULL; }
      }
    }
  } else {
    // rare fallback: full cost scan (original semantics, all tiers)
    unsigned long long kv[10];
    #pragma unroll
    for (int k = 0; k < 10; k++) kv[k] = ~0ULL;
    for (int j = tid; j < F; j += 256) {
      float4 B = CB[j];
      float4 M = CM[j];
      float Dv = CD[j];
      int a = __float_as_int(M.w);
      float b1x = B.x - B.z*0.5f, b1y = B.y - B.w*0.5f;
      float b2x = B.x + B.z*0.5f, b2y = B.y + B.w*0.5f;
      float wx = fminf(a2x, b2x) - fmaxf(a1x, b1x); wx = wx > 0.f ? wx : 0.f;
      float wy = fminf(a2y, b2y) - fmaxf(a1y, b1y); wy = wy > 0.f ? wy : 0.f;
      float inter = wx * wy;
      float iou = inter / (garea + B.z*B.w - inter + 1e-8f);
      float xc = M.x, yc = M.y;
      float rad = (a < 25600) ? 20.f : ((a < 32000) ? 40.f : 80.f);
      bool inb = fminf(fminf(xc - a1x, a2x - xc), fminf(yc - a1y, a2y - yc)) > 0.f;
      bool inc = fminf(fminf(xc - gx + rad, gx + rad - xc), fminf(yc - gy + rad, gy + rad - yc)) > 0.f;
      float cost = -(Dv + M.z) + 3.0f * (-__logf(iou + 1e-8f));
      if (!(inb && inc)) cost += 100000.0f;
      unsigned long long key = ((unsigned long long)fkey(cost) << 32) | (unsigned int)a;
      if (key < kv[9]) {
        kv[9] = key;
        #pragma unroll
        for (int k = 9; k > 0; k--) {
          if (kv[k] < kv[k-1]) { unsigned long long t = kv[k]; kv[k] = kv[k-1]; kv[k-1] = t; }
        }
      }
    }
    // per-wave ascending extraction -> sorted list in LDS
    for (int k = 0; k < 10; k++) {
      unsigned long long m = kv[0];
      #pragma unroll
      for (int d = 1; d < 64; d <<= 1) {
        unsigned long long o = __shfl_xor(m, d);
        if (o < m) m = o;
      }
      if (lane == 0) kvl[wv][k] = m;
      if (kv[0] == m) {
        #pragma unroll
        for (int j2 = 0; j2 < 9; j2++) kv[j2] = kv[j2+1];
        kv[9] = ~0ULL;
      }
    }
    __syncthreads();
    if (tid == 0) {
      int p_[4] = {0,0,0,0};
      #pragma unroll 1
      for (int k = 0; k < dynk; k++) {
        unsigned long long best = kvl[0][p_[0]]; int bl = 0;
        #pragma unroll
        for (int l = 1; l < 4; l++) {
          unsigned long long v = kvl[l][p_[l]];
          if (v < best) { best = v; bl = l; }
        }
        if (best == ~0ULL) break;         // defensive
        int a = (int)(unsigned int)(best & 0xFFFFFFFFu);
        atomicAdd(&g_nmatch[b*NA + a], 1);
        atomicAdd(&g_gsum[b*NA + a], g);
        if (p_[bl] < 9) p_[bl]++;
        else kvl[bl][9] = ~0ULL;          // list exhausted
      }
    }
  }
}

// ---- Kernel C: dedup (argmin over g), per-anchor losses, per-block partial store ----
__global__ __launch_bounds__(256) void loss_kernel(const float* __restrict__ p0,
                                                   const float* __restrict__ p1,
                                                   const float* __restrict__ p2,
                                                   const float* __restrict__ lb) {
  __shared__ float  lab[NG*5];
  __shared__ int    lval[NG];
  __shared__ double red[256*4];
  int b = blockIdx.y, tid = threadIdx.x;
  for (int i = tid; i < NG*5; i += 256) lab[i] = lb[(size_t)b*NG*5 + i];
  __syncthreads();
  if (tid < NG) {
    float s = lab[tid*5] + lab[tid*5+1] + lab[tid*5+2] + lab[tid*5+3] + lab[tid*5+4];
    lval[tid] = (s > 0.f) ? 1 : 0;
  }
  __syncthreads();

  int a = blockIdx.x * 256 + tid;
  double t_nfg = 0.0, t_iou = 0.0, t_obj = 0.0, t_cls = 0.0;

  if (a < NA) {
    int idx = b * NA + a;
    int H, W, h, w, lvl; float st;
    anchor_geom(a, H, W, st, h, w, lvl);
    const float* pp = (lvl == 0) ? p0 : ((lvl == 1) ? p1 : p2);
    size_t cs = (size_t)H * W;
    size_t base = (size_t)b * 15 * cs + (size_t)h * W + w;

    float x  = pp[base + 4*cs];
    int   nm = g_nmatch[idx];
    float t  = (nm > 0) ? 1.f : 0.f;
    float bce = fmaxf(x, 0.f) - x * t + log1pf(expf(-fabsf(x)));
    float pr  = 1.f / (1.f + expf(-x));
    float pt  = (nm > 0) ? pr : (1.f - pr);
    float wf  = (nm > 0) ? 0.25f : 0.75f;
    float om  = 1.f - pt;
    t_obj = (double)(bce * wf * om * om);

    if (nm > 0) {
      t_nfg = 1.0;
      int mgsum = g_gsum[idx];
      g_nmatch[idx] = 0;           // self-clean for next call
      g_gsum[idx]   = 0;
      int j = g_slot[idx];
      float4 B  = g_cbox [(size_t)b*NA + j];
      float4 Mt = g_cmeta[(size_t)b*NA + j];
      float pw = B.z, ph = B.w;
      float b1x = B.x - pw*0.5f, b1y = B.y - ph*0.5f, b2x = B.x + pw*0.5f, b2y = B.y + ph*0.5f;
      int mg;
      if (nm == 1) {
        mg = mgsum;
      } else {
        // matched => fg, so the 1e6 term reduces to validity only
        float xc = Mt.x, yc = Mt.y, S = Mt.z;
        float rad = 2.5f * st;
        const float* CDb = &g_cD[(size_t)b*NCLS*NA];
        float best = INFINITY; int bg = 0;
        for (int g = 0; g < NG; g++) {
          float gx = lab[g*5+1], gy = lab[g*5+2], gw = lab[g*5+3], gh = lab[g*5+4];
          int gcl = (int)lab[g*5];
          int v = lval[g];
          float a1x = gx - gw*0.5f, a1y = gy - gh*0.5f, a2x = gx + gw*0.5f, a2y = gy + gh*0.5f;
          float wx = fminf(a2x, b2x) - fmaxf(a1x, b1x); wx = wx > 0.f ? wx : 0.f;
          float wy = fminf(a2y, b2y) - fmaxf(a1y, b1y); wy = wy > 0.f ? wy : 0.f;
          float inter = wx * wy;
          float iou = inter / (gw*gh + pw*ph - inter + 1e-8f);
          float l = xc - a1x, r = a2x - xc, tt = yc - a1y, bo = a2y - yc;
          bool inb = (fminf(fminf(l, r), fminf(tt, bo)) > 0.f) && v;
          float cl = xc - gx + rad, cr = gx + rad - xc, ct = yc - gy + rad, cb = gy + rad - yc;
          bool inc = (fminf(fminf(cl, cr), fminf(ct, cb)) > 0.f) && v;
          float clsc = -(CDb[(size_t)gcl*NA + j] + S);
          float cost = clsc + 3.0f * (-__logf(iou + 1e-8f));
          if (!(inb && inc)) cost += 100000.0f;
          if (!v)            cost += 1000000.0f;
          if (cost < best) { best = cost; bg = g; }   // strict < : first-index tie-break
        }
        mg = bg;
      }

      float gx = lab[mg*5+1], gy = lab[mg*5+2], gw = lab[mg*5+3], gh = lab[mg*5+4];
      int mcls = (int)lab[mg*5];
      float a1x = gx - gw*0.5f, a1y = gy - gh*0.5f, a2x = gx + gw*0.5f, a2y = gy + gh*0.5f;
      float wx = fminf(a2x, b2x) - fmaxf(a1x, b1x); wx = wx > 0.f ? wx : 0.f;
      float wy = fminf(a2y, b2y) - fmaxf(a1y, b1y); wy = wy > 0.f ? wy : 0.f;
      float inter = wx * wy;
      float miou = inter / (gw*gh + pw*ph - inter + 1e-8f);  // == forward-loss IoU bit-exact

      t_iou = (double)(1.f - miou * miou);

      float sc = 0.f;
      #pragma unroll
      for (int c = 0; c < NCLS; c++) {
        float xl = pp[base + (size_t)(5 + c) * cs];
        float ctg = (c == mcls) ? miou : 0.f;
        sc += fmaxf(xl, 0.f) - xl * ctg + log1pf(expf(-fabsf(xl)));
      }
      t_cls = (double)sc;
    }
  }

  red[tid] = t_nfg; red[256+tid] = t_iou; red[512+tid] = t_obj; red[768+tid] = t_cls;
  __syncthreads();
  for (int s = 128; s > 0; s >>= 1) {
    if (tid < s) {
      red[tid]     += red[tid+s];
      red[256+tid] += red[256+tid+s];
      red[512+tid] += red[512+tid+s];
      red[768+tid] += red[768+tid+s];
    }
    __syncthreads();
  }
  if (tid == 0) {
    int blk = b * NBLK_X + blockIdx.x;
    g_part[blk][0] = red[0];
    g_part[blk][1] = red[256];
    g_part[blk][2] = red[512];
    g_part[blk][3] = red[768];
  }
}

// ---- Kernel D: reduce per-block partials, finalize, reset fcount ----
__global__ __launch_bounds__(256) void final_kernel(float* __restrict__ out) {
  __shared__ double red[256];
  int tid = threadIdx.x;
  int cat = tid & 3;
  double s = 0.0;
  for (int blk = tid >> 2; blk < NBLK_LOSS; blk += 64) s += g_part[blk][cat];
  red[tid] = s;
  __syncthreads();
  for (int st = 128; st >= 4; st >>= 1) {
    if (tid < st) red[tid] += red[tid + st];
    __syncthreads();
  }
  if (tid == 0) {
    double nfg = red[0];
    double num = (nfg < 1.0) ? 1.0 : nfg;
    float li = (float)(red[1] / num);
    float lo = (float)(red[2] / num);
    float lc = (float)(red[3] / num);
    out[0] = 5.0f * li + lo;   // REG_W * loss_iou + loss_obj
    out[1] = li;
    out[2] = lo;
    out[3] = lc;
  }
  if (tid < NB) g_fcount[tid] = 0;   // self-restore for next call
}

extern "C" void kernel_launch(void* const* d_in, const int* in_sizes, int n_in,
                              void* d_out, int out_size, void* d_ws, size_t ws_size,
                              hipStream_t stream) {
  const float* p0 = (const float*)d_in[0];
  const float* p1 = (const float*)d_in[1];
  const float* p2 = (const float*)d_in[2];
  const float* lb = (const float*)d_in[3];
  float* out = (float*)d_out;

  hipLaunchKernelGGL(decode_kernel, dim3(NBLK_X, NB), dim3(256), 0, stream, p0, p1, p2, lb);
  hipLaunchKernelGGL(topk_kernel,   dim3(NB*NG), dim3(256), 0, stream, lb);
  hipLaunchKernelGGL(loss_kernel,   dim3(NBLK_X, NB), dim3(256), 0, stream, p0, p1, p2, lb);
  hipLaunchKernelGGL(final_kernel,  dim3(1), dim3(256), 0, stream, out);
}

// Round 11
// 172.742 us; speedup vs baseline: 2.2037x; 1.0960x over previous
//
#include <hip/hip_runtime.h>
#include <math.h>

#define NCLS 10
#define NB   16
#define NG   60
#define NA   33600          // 160*160 + 80*80 + 40*40
#define BA   (NB*NA)        // 537600
#define NBLK_X 132          // ceil(NA/256)
#define NBLK_LOSS (NBLK_X*NB)
#define TKW  8              // waves per topk block (512 threads)

// ---- static device scratch (load-time zero; self-restoring across calls) ----
__device__ double g_part[NBLK_LOSS][4];     // per-loss-block partials (nfg, iou, obj, cls)
__device__ int    g_fcount[NB];             // fg count per image (reset by final_kernel)
__device__ int    g_nmatch[BA];             // all-zero between calls (self-cleaned by loss)
__device__ int    g_gsum[BA];               // all-zero between calls (self-cleaned by loss)
__device__ int    g_slot[BA];               // compact slot (valid for fg anchors only)
// compacted per-image fg-anchor data
__device__ float4 g_cbox [BA];              // [b][j] bx,by,bw,bh
__device__ float4 g_cmeta[BA];              // [b][j] xc, yc, S, anchor_id_bits
__device__ float  g_cD   [(size_t)NB*NCLS*NA];  // [b][c][j] class-major

__device__ __forceinline__ void anchor_geom(int a, int& H, int& W, float& s, int& h, int& w, int& lvl) {
  if (a < 25600)      { lvl = 0; H = 160; W = 160; s = 8.f;  h = a / 160;            w = a - h*160; }
  else if (a < 32000) { lvl = 1; H = 80;  W = 80;  s = 16.f; int r = a - 25600; h = r / 80;  w = r - h*80; }
  else                { lvl = 2; H = 40;  W = 40;  s = 32.f; int r = a - 32000; h = r / 40;  w = r - h*40; }
}

// monotone float->uint key (order-preserving for all finite floats)
__device__ __forceinline__ unsigned int fkey(float f) {
  unsigned int b = __float_as_uint(f);
  return (b & 0x80000000u) ? ~b : (b | 0x80000000u);
}

// ---- Kernel A: y-band GT filter -> fg test -> compact -> decode planes (fg only) ----
__global__ __launch_bounds__(256) void decode_kernel(const float* __restrict__ p0,
                                                     const float* __restrict__ p1,
                                                     const float* __restrict__ p2,
                                                     const float* __restrict__ lb) {
  __shared__ float lab[NG*5];
  __shared__ int   glist[NG];
  __shared__ int   gln;
  __shared__ int   wbase[4];
  __shared__ int   bbase_s;
  int b = blockIdx.y, tid = threadIdx.x;
  for (int i = tid; i < NG*5; i += 256) lab[i] = lb[(size_t)b*NG*5 + i];
  if (tid == 0) gln = 0;
  __syncthreads();

  // block anchor-band geometry (level boundaries 25600, 32000 are 256-aligned)
  int a0 = blockIdx.x * 256;
  int H, W, h0, w0, lvl; float st;
  anchor_geom(a0, H, W, st, h0, w0, lvl);
  int aL = a0 + 255; if (aL >= NA) aL = NA - 1;
  int Hx, Wx, h1, w1, l1; float st1;
  anchor_geom(aL, Hx, Wx, st1, h1, w1, l1);
  float ylo = ((float)h0 + 0.5f) * st;
  float yhi = ((float)h1 + 0.5f) * st;
  float rad = 2.5f * st;

  // per-GT y-band relevance filter (conservative)
  if (tid < NG) {
    float s0 = lab[tid*5] + lab[tid*5+1] + lab[tid*5+2] + lab[tid*5+3] + lab[tid*5+4];
    if (s0 > 0.f) {
      float gy = lab[tid*5+2], gh = lab[tid*5+4];
      float m = fmaxf(gh * 0.5f, rad);
      if ((gy - m < yhi) && (gy + m > ylo)) {
        int p = atomicAdd(&gln, 1);
        glist[p] = tid;
      }
    }
  }
  __syncthreads();

  int n = gln;
  if (n == 0) return;   // no GT can touch this band -> no fg anchors here

  int a = a0 + tid;
  bool valid = a < NA;
  int H2, W2, ht, wt, l2; float st2;
  anchor_geom(valid ? a : a0, H2, W2, st2, ht, wt, l2);
  float xc = ((float)wt + 0.5f) * st;
  float yc = ((float)ht + 0.5f) * st;

  int fg = 0;
  if (valid) {
    for (int q = 0; q < n; q++) {
      int g = glist[q];
      float gx = lab[g*5+1], gy = lab[g*5+2], gw = lab[g*5+3], gh = lab[g*5+4];
      float l  = xc - (gx - gw*0.5f);
      float r  = (gx + gw*0.5f) - xc;
      float t  = yc - (gy - gh*0.5f);
      float bo = (gy + gh*0.5f) - yc;
      float m1 = fminf(fminf(l, r), fminf(t, bo));
      float cl = xc - gx + rad, cr = gx + rad - xc, ct = yc - gy + rad, cb = gy + rad - yc;
      float m2 = fminf(fminf(cl, cr), fminf(ct, cb));
      if (m1 > 0.f || m2 > 0.f) { fg = 1; break; }
    }
  }

  // block-aggregated compaction: one atomic per block
  unsigned long long m = __ballot(fg != 0);
  int lane = tid & 63, wv = tid >> 6;
  if (lane == 0) wbase[wv] = __popcll(m);
  __syncthreads();
  if (tid == 0) {
    int t = 0;
    #pragma unroll
    for (int k = 0; k < 4; k++) { int c = wbase[k]; wbase[k] = t; t += c; }
    bbase_s = t ? atomicAdd(&g_fcount[b], t) : 0;
  }
  __syncthreads();

  if (fg) {
    // plane loads + transcendentals only for fg anchors
    const float* pp = (lvl == 0) ? p0 : ((lvl == 1) ? p1 : p2);
    size_t cs = (size_t)H * W;
    size_t base = (size_t)b * 15 * cs + (size_t)ht * W + wt;

    float tx = pp[base], ty = pp[base+cs], tw = pp[base+2*cs], th = pp[base+3*cs], to = pp[base+4*cs];
    float4 boxv = make_float4((tx + (float)wt) * st, (ty + (float)ht) * st,
                              __expf(tw) * st, __expf(th) * st);

    float so = 1.f / (1.f + __expf(-to));
    float S = 0.f;
    float Dl[NCLS];
    #pragma unroll
    for (int c = 0; c < NCLS; c++) {
      float xl = pp[base + (size_t)(5 + c) * cs];
      float sc = 1.f / (1.f + __expf(-xl));
      float p  = sqrtf(sc * so);
      float L  = __logf(p + 1e-12f);
      float M  = __logf(1.f - p + 1e-12f);
      S += M;
      Dl[c] = L - M;
    }

    int j = bbase_s + wbase[wv] + (int)__popcll(m & ((1ULL << lane) - 1ULL));
    size_t cb = (size_t)b * NA + j;
    g_cbox[cb]  = boxv;
    g_cmeta[cb] = make_float4(xc, yc, S, __int_as_float(a));
    #pragma unroll
    for (int c = 0; c < NCLS; c++) g_cD[((size_t)b*NCLS + c)*NA + j] = Dl[c];
    g_slot[b * NA + a] = j;
  }
}

// ---- Kernel B: per-(b,g) 512-thread block: tier-1 enum + pipelined iou scan + dyn_k + scatter ----
__global__ __launch_bounds__(512) void topk_kernel(const float* __restrict__ lb) {
  __shared__ unsigned long long keyarr[128];
  __shared__ unsigned long long kvl[TKW][10];
  __shared__ float              ioul[TKW][10];
  __shared__ int                wcnt[2];
  __shared__ int                sdynk;
  __shared__ int                st1cnt;

  int fid = blockIdx.x;                 // XCD-clustering remap: images {2r,2r+1} -> XCD r
  int t8 = fid >> 3;
  int b  = ((fid & 7) << 1) + (t8 >= 60 ? 1 : 0);
  int g  = t8 - (t8 >= 60 ? 60 : 0);
  int tid = threadIdx.x, lane = tid & 63, wv = tid >> 6;

  const float* L = &lb[((size_t)b*NG + g)*5];
  float l0 = L[0], l1 = L[1], l2 = L[2], l3 = L[3], l4 = L[4];
  if (!(l0 + l1 + l2 + l3 + l4 > 0.f)) return;

  int   gc = (int)l0;
  float gx = l1, gy = l2, gw = l3, gh = l4;
  float a1x = gx - gw*0.5f, a1y = gy - gh*0.5f, a2x = gx + gw*0.5f, a2y = gy + gh*0.5f;
  float garea = gw * gh;
  int F = g_fcount[b];
  const float4* CB = &g_cbox [(size_t)b*NA];
  const float4* CM = &g_cmeta[(size_t)b*NA];
  const float*  CD = &g_cD[((size_t)b*NCLS + gc)*NA];

  // ---- Phase E: tier-1 (in_box && in_ctr) enumeration, one cell per thread (tids 0..107) ----
  unsigned long long t1key = ~0ULL;
  if (tid < 108) {
    int lv   = tid / 36;                 // 0..2
    int cell = tid - lv*36;              // 0..35
    int dy   = cell / 6 - 2;             // -2..3
    int dx   = cell - (cell/6)*6 - 2;    // -2..3
    int   W  = (lv == 0) ? 160 : ((lv == 1) ? 80 : 40);
    float st = (lv == 0) ? 8.f : ((lv == 1) ? 16.f : 32.f);
    int   ab = (lv == 0) ? 0 : ((lv == 1) ? 25600 : 32000);
    int wc = (int)floorf(gx / st - 0.5f) + dx;
    int hc = (int)floorf(gy / st - 0.5f) + dy;
    if (wc >= 0 && wc < W && hc >= 0 && hc < W) {
      float xc = ((float)wc + 0.5f) * st;
      float yc = ((float)hc + 0.5f) * st;
      float rad = 2.5f * st;
      bool inb = fminf(fminf(xc - a1x, a2x - xc), fminf(yc - a1y, a2y - yc)) > 0.f;
      bool inc = fminf(fminf(xc - gx + rad, gx + rad - xc), fminf(yc - gy + rad, gy + rad - yc)) > 0.f;
      if (inb && inc) {
        int a = ab + hc * W + wc;        // in_ctr => fg => slot valid
        int j = g_slot[b*NA + a];
        float4 B = CB[j];
        float Dv = CD[j];
        float S  = CM[j].z;
        float b1x = B.x - B.z*0.5f, b1y = B.y - B.w*0.5f;
        float b2x = B.x + B.z*0.5f, b2y = B.y + B.w*0.5f;
        float wx = fminf(a2x, b2x) - fmaxf(a1x, b1x); wx = wx > 0.f ? wx : 0.f;
        float wy = fminf(a2y, b2y) - fmaxf(a1y, b1y); wy = wy > 0.f ? wy : 0.f;
        float inter = wx * wy;
        float iou = inter / (garea + B.z*B.w - inter + 1e-8f);
        float cost = -(Dv + S) + 3.0f * (-__logf(iou + 1e-8f));   // tier-1: no penalties
        t1key = ((unsigned long long)fkey(cost) << 32) | (unsigned int)a;
      }
    }
  }
  if (tid < 128) keyarr[tid] = t1key;
  if (wv < 2) {
    unsigned long long bal = __ballot(t1key != ~0ULL);
    if (lane == 0) wcnt[wv] = __popcll(bal);
  }

  // ---- Phase S: software-pipelined iou-only scan over compacted fg anchors ----
  float iv[10];
  #pragma unroll
  for (int k = 0; k < 10; k++) iv[k] = 0.f;
  {
    int j = tid;
    float4 Bc = make_float4(0.f, 0.f, 0.f, 0.f);
    if (j < F) Bc = CB[j];
    while (j < F) {
      int jn = j + 512;
      float4 Bn = make_float4(0.f, 0.f, 0.f, 0.f);
      if (jn < F) Bn = CB[jn];              // prefetch next stripe
      float b1x = Bc.x - Bc.z*0.5f, b1y = Bc.y - Bc.w*0.5f;
      float b2x = Bc.x + Bc.z*0.5f, b2y = Bc.y + Bc.w*0.5f;
      float wx = fminf(a2x, b2x) - fmaxf(a1x, b1x); wx = wx > 0.f ? wx : 0.f;
      float wy = fminf(a2y, b2y) - fmaxf(a1y, b1y); wy = wy > 0.f ? wy : 0.f;
      float inter = wx * wy;
      float iou = inter / (garea + Bc.z*Bc.w - inter + 1e-8f);
      if (iou > iv[9]) {
        iv[9] = iou;
        #pragma unroll
        for (int k = 9; k > 0; k--) {
          if (iv[k] > iv[k-1]) { float t = iv[k]; iv[k] = iv[k-1]; iv[k-1] = t; }
        }
      }
      Bc = Bn; j = jn;
    }
  }
  // per-wave descending extraction -> sorted list in LDS
  for (int k = 0; k < 10; k++) {
    float m = iv[0];
    #pragma unroll
    for (int d = 1; d < 64; d <<= 1) m = fmaxf(m, __shfl_xor(m, d));
    if (lane == 0) ioul[wv][k] = m;
    unsigned long long pm = __ballot(iv[0] == m);
    if (lane == __ffsll((unsigned long long)pm) - 1) {
      #pragma unroll
      for (int j2 = 0; j2 < 9; j2++) iv[j2] = iv[j2+1];
      iv[9] = 0.f;
    }
  }
  __syncthreads();

  // tid 0: merge TKW sorted iou lists (descending) -> dyn_k
  if (tid == 0) {
    st1cnt = wcnt[0] + wcnt[1];
    int p_[TKW];
    #pragma unroll
    for (int l = 0; l < TKW; l++) p_[l] = 0;
    float ss = 0.f;
    #pragma unroll 1
    for (int k = 0; k < 10; k++) {
      float best = ioul[0][p_[0]]; int bl = 0;
      #pragma unroll
      for (int l = 1; l < TKW; l++) {
        float v = ioul[l][p_[l]];
        if (v > best) { best = v; bl = l; }
      }
      ss += best;                         // descending order, same sum order as ref
      if (p_[bl] < 9) p_[bl]++;
      else ioul[bl][9] = -INFINITY;       // list exhausted
    }
    int dynk = (int)ss;
    if (dynk < 1)  dynk = 1;
    if (dynk > 10) dynk = 10;
    sdynk = dynk;
  }
  __syncthreads();
  int dynk  = sdynk;
  int t1cnt = st1cnt;

  if (t1cnt >= 10) {
    // cost top-10 is entirely tier-1 (tier-2 >= 1e5 > any tier-1 cost <= ~332)
    if (wv == 0) {
      unsigned long long q0 = keyarr[lane], q1 = keyarr[lane+64];
      if (q1 < q0) { unsigned long long t = q0; q0 = q1; q1 = t; }
      for (int k = 0; k < dynk; k++) {
        unsigned long long m = q0;
        #pragma unroll
        for (int d = 1; d < 64; d <<= 1) {
          unsigned long long o = __shfl_xor(m, d);
          if (o < m) m = o;
        }
        if (m == ~0ULL) break;            // defensive
        if (lane == 0) {
          int a = (int)(unsigned int)(m & 0xFFFFFFFFu);
          atomicAdd(&g_nmatch[b*NA + a], 1);
          atomicAdd(&g_gsum[b*NA + a], g);
        }
        if (q0 == m) { q0 = q1; q1 = ~0ULL; }
      }
    }
  } else {
    // rare fallback: full cost scan (original semantics, all tiers)
    unsigned long long kv[10];
    #pragma unroll
    for (int k = 0; k < 10; k++) kv[k] = ~0ULL;
    for (int j = tid; j < F; j += 512) {
      float4 B = CB[j];
      float4 M = CM[j];
      float Dv = CD[j];
      int a = __float_as_int(M.w);
      float b1x = B.x - B.z*0.5f, b1y = B.y - B.w*0.5f;
      float b2x = B.x + B.z*0.5f, b2y = B.y + B.w*0.5f;
      float wx = fminf(a2x, b2x) - fmaxf(a1x, b1x); wx = wx > 0.f ? wx : 0.f;
      float wy = fminf(a2y, b2y) - fmaxf(a1y, b1y); wy = wy > 0.f ? wy : 0.f;
      float inter = wx * wy;
      float iou = inter / (garea + B.z*B.w - inter + 1e-8f);
      float xc = M.x, yc = M.y;
      float rad = (a < 25600) ? 20.f : ((a < 32000) ? 40.f : 80.f);
      bool inb = fminf(fminf(xc - a1x, a2x - xc), fminf(yc - a1y, a2y - yc)) > 0.f;
      bool inc = fminf(fminf(xc - gx + rad, gx + rad - xc), fminf(yc - gy + rad, gy + rad - yc)) > 0.f;
      float cost = -(Dv + M.z) + 3.0f * (-__logf(iou + 1e-8f));
      if (!(inb && inc)) cost += 100000.0f;
      unsigned long long key = ((unsigned long long)fkey(cost) << 32) | (unsigned int)a;
      if (key < kv[9]) {
        kv[9] = key;
        #pragma unroll
        for (int k = 9; k > 0; k--) {
          if (kv[k] < kv[k-1]) { unsigned long long t = kv[k]; kv[k] = kv[k-1]; kv[k-1] = t; }
        }
      }
    }
    // per-wave ascending extraction -> sorted list in LDS
    for (int k = 0; k < 10; k++) {
      unsigned long long m = kv[0];
      #pragma unroll
      for (int d = 1; d < 64; d <<= 1) {
        unsigned long long o = __shfl_xor(m, d);
        if (o < m) m = o;
      }
      if (lane == 0) kvl[wv][k] = m;
      if (kv[0] == m) {
        #pragma unroll
        for (int j2 = 0; j2 < 9; j2++) kv[j2] = kv[j2+1];
        kv[9] = ~0ULL;
      }
    }
    __syncthreads();
    if (tid == 0) {
      int p_[TKW];
      #pragma unroll
      for (int l = 0; l < TKW; l++) p_[l] = 0;
      #pragma unroll 1
      for (int k = 0; k < dynk; k++) {
        unsigned long long best = kvl[0][p_[0]]; int bl = 0;
        #pragma unroll
        for (int l = 1; l < TKW; l++) {
          unsigned long long v = kvl[l][p_[l]];
          if (v < best) { best = v; bl = l; }
        }
        if (best == ~0ULL) break;         // defensive
        int a = (int)(unsigned int)(best & 0xFFFFFFFFu);
        atomicAdd(&g_nmatch[b*NA + a], 1);
        atomicAdd(&g_gsum[b*NA + a], g);
        if (p_[bl] < 9) p_[bl]++;
        else kvl[bl][9] = ~0ULL;          // list exhausted
      }
    }
  }
}

// ---- Kernel C: dedup (argmin over g), per-anchor losses, wave-reduce, per-block partial ----
__global__ __launch_bounds__(256) void loss_kernel(const float* __restrict__ p0,
                                                   const float* __restrict__ p1,
                                                   const float* __restrict__ p2,
                                                   const float* __restrict__ lb) {
  __shared__ float  lab[NG*5];
  __shared__ int    lval[NG];
  __shared__ double wred[4][4];
  int b = blockIdx.y, tid = threadIdx.x;
  for (int i = tid; i < NG*5; i += 256) lab[i] = lb[(size_t)b*NG*5 + i];
  __syncthreads();
  if (tid < NG) {
    float s = lab[tid*5] + lab[tid*5+1] + lab[tid*5+2] + lab[tid*5+3] + lab[tid*5+4];
    lval[tid] = (s > 0.f) ? 1 : 0;
  }
  __syncthreads();

  int a = blockIdx.x * 256 + tid;
  double t_nfg = 0.0, t_iou = 0.0, t_obj = 0.0, t_cls = 0.0;

  if (a < NA) {
    int idx = b * NA + a;
    int H, W, h, w, lvl; float st;
    anchor_geom(a, H, W, st, h, w, lvl);
    const float* pp = (lvl == 0) ? p0 : ((lvl == 1) ? p1 : p2);
    size_t cs = (size_t)H * W;
    size_t base = (size_t)b * 15 * cs + (size_t)h * W + w;

    float x  = pp[base + 4*cs];
    int   nm = g_nmatch[idx];
    float t  = (nm > 0) ? 1.f : 0.f;
    float bce = fmaxf(x, 0.f) - x * t + log1pf(expf(-fabsf(x)));
    float pr  = 1.f / (1.f + expf(-x));
    float pt  = (nm > 0) ? pr : (1.f - pr);
    float wf  = (nm > 0) ? 0.25f : 0.75f;
    float om  = 1.f - pt;
    t_obj = (double)(bce * wf * om * om);

    if (nm > 0) {
      t_nfg = 1.0;
      int mgsum = g_gsum[idx];
      g_nmatch[idx] = 0;           // self-clean for next call
      g_gsum[idx]   = 0;
      int j = g_slot[idx];
      float4 B  = g_cbox [(size_t)b*NA + j];
      float4 Mt = g_cmeta[(size_t)b*NA + j];
      float pw = B.z, ph = B.w;
      float b1x = B.x - pw*0.5f, b1y = B.y - ph*0.5f, b2x = B.x + pw*0.5f, b2y = B.y + ph*0.5f;
      int mg;
      if (nm == 1) {
        mg = mgsum;
      } else {
        // matched => fg, so the 1e6 term reduces to validity only
        float xc = Mt.x, yc = Mt.y, S = Mt.z;
        float rad = 2.5f * st;
        const float* CDb = &g_cD[(size_t)b*NCLS*NA];
        float best = INFINITY; int bg = 0;
        for (int g = 0; g < NG; g++) {
          float gx = lab[g*5+1], gy = lab[g*5+2], gw = lab[g*5+3], gh = lab[g*5+4];
          int gcl = (int)lab[g*5];
          int v = lval[g];
          float a1x = gx - gw*0.5f, a1y = gy - gh*0.5f, a2x = gx + gw*0.5f, a2y = gy + gh*0.5f;
          float wx = fminf(a2x, b2x) - fmaxf(a1x, b1x); wx = wx > 0.f ? wx : 0.f;
          float wy = fminf(a2y, b2y) - fmaxf(a1y, b1y); wy = wy > 0.f ? wy : 0.f;
          float inter = wx * wy;
          float iou = inter / (gw*gh + pw*ph - inter + 1e-8f);
          float l = xc - a1x, r = a2x - xc, tt = yc - a1y, bo = a2y - yc;
          bool inb = (fminf(fminf(l, r), fminf(tt, bo)) > 0.f) && v;
          float cl = xc - gx + rad, cr = gx + rad - xc, ct = yc - gy + rad, cb = gy + rad - yc;
          bool inc = (fminf(fminf(cl, cr), fminf(ct, cb)) > 0.f) && v;
          float clsc = -(CDb[(size_t)gcl*NA + j] + S);
          float cost = clsc + 3.0f * (-__logf(iou + 1e-8f));
          if (!(inb && inc)) cost += 100000.0f;
          if (!v)            cost += 1000000.0f;
          if (cost < best) { best = cost; bg = g; }   // strict < : first-index tie-break
        }
        mg = bg;
      }

      float gx = lab[mg*5+1], gy = lab[mg*5+2], gw = lab[mg*5+3], gh = lab[mg*5+4];
      int mcls = (int)lab[mg*5];
      float a1x = gx - gw*0.5f, a1y = gy - gh*0.5f, a2x = gx + gw*0.5f, a2y = gy + gh*0.5f;
      float wx = fminf(a2x, b2x) - fmaxf(a1x, b1x); wx = wx > 0.f ? wx : 0.f;
      float wy = fminf(a2y, b2y) - fmaxf(a1y, b1y); wy = wy > 0.f ? wy : 0.f;
      float inter = wx * wy;
      float miou = inter / (gw*gh + pw*ph - inter + 1e-8f);  // == forward-loss IoU bit-exact

      t_iou = (double)(1.f - miou * miou);

      float sc = 0.f;
      #pragma unroll
      for (int c = 0; c < NCLS; c++) {
        float xl = pp[base + (size_t)(5 + c) * cs];
        float ctg = (c == mcls) ? miou : 0.f;
        sc += fmaxf(xl, 0.f) - xl * ctg + log1pf(expf(-fabsf(xl)));
      }
      t_cls = (double)sc;
    }
  }

  // in-wave reduction (no barriers), then one barrier + tid0 sum of 4 wave-partials
  #pragma unroll
  for (int d = 32; d > 0; d >>= 1) {
    t_nfg += __shfl_down(t_nfg, d);
    t_iou += __shfl_down(t_iou, d);
    t_obj += __shfl_down(t_obj, d);
    t_cls += __shfl_down(t_cls, d);
  }
  int lane = tid & 63, wv = tid >> 6;
  if (lane == 0) {
    wred[wv][0] = t_nfg; wred[wv][1] = t_iou; wred[wv][2] = t_obj; wred[wv][3] = t_cls;
  }
  __syncthreads();
  if (tid == 0) {
    int blk = b * NBLK_X + blockIdx.x;
    g_part[blk][0] = wred[0][0] + wred[1][0] + wred[2][0] + wred[3][0];
    g_part[blk][1] = wred[0][1] + wred[1][1] + wred[2][1] + wred[3][1];
    g_part[blk][2] = wred[0][2] + wred[1][2] + wred[2][2] + wred[3][2];
    g_part[blk][3] = wred[0][3] + wred[1][3] + wred[2][3] + wred[3][3];
  }
}

// ---- Kernel D: reduce per-block partials, finalize, reset fcount ----
__global__ __launch_bounds__(256) void final_kernel(float* __restrict__ out) {
  __shared__ double red[256];
  int tid = threadIdx.x;
  int cat = tid & 3;
  double s = 0.0;
  for (int blk = tid >> 2; blk < NBLK_LOSS; blk += 64) s += g_part[blk][cat];
  red[tid] = s;
  __syncthreads();
  for (int st = 128; st >= 4; st >>= 1) {
    if (tid < st) red[tid] += red[tid + st];
    __syncthreads();
  }
  if (tid == 0) {
    double nfg = red[0];
    double num = (nfg < 1.0) ? 1.0 : nfg;
    float li = (float)(red[1] / num);
    float lo = (float)(red[2] / num);
    float lc = (float)(red[3] / num);
    out[0] = 5.0f * li + lo;   // REG_W * loss_iou + loss_obj
    out[1] = li;
    out[2] = lo;
    out[3] = lc;
  }
  if (tid < NB) g_fcount[tid] = 0;   // self-restore for next call
}

extern "C" void kernel_launch(void* const* d_in, const int* in_sizes, int n_in,
                              void* d_out, int out_size, void* d_ws, size_t ws_size,
                              hipStream_t stream) {
  const float* p0 = (const float*)d_in[0];
  const float* p1 = (const float*)d_in[1];
  const float* p2 = (const float*)d_in[2];
  const float* lb = (const float*)d_in[3];
  float* out = (float*)d_out;

  hipLaunchKernelGGL(decode_kernel, dim3(NBLK_X, NB), dim3(256), 0, stream, p0, p1, p2, lb);
  hipLaunchKernelGGL(topk_kernel,   dim3(NB*NG), dim3(512), 0, stream, lb);
  hipLaunchKernelGGL(loss_kernel,   dim3(NBLK_X, NB), dim3(256), 0, stream, p0, p1, p2, lb);
  hipLaunchKernelGGL(final_kernel,  dim3(1), dim3(256), 0, stream, out);
}